// Round 5
// baseline (144.211 us; speedup 1.0000x reference)
//
#include <hip/hip_runtime.h>

typedef unsigned short u16;
typedef __attribute__((ext_vector_type(8))) __bf16 bf16x8;
typedef __attribute__((ext_vector_type(4))) float f32x4;
typedef __attribute__((ext_vector_type(4))) int i32x4;

#define MFMA16(a, b, c) __builtin_amdgcn_mfma_f32_16x16x32_bf16(a, b, c, 0, 0, 0)

__device__ __forceinline__ u16 f2b(float f) {
  __bf16 h = (__bf16)f;
  return __builtin_bit_cast(u16, h);
}

// global -> LDS direct (wave-uniform LDS base + lane*16; global addr per-lane)
__device__ __forceinline__ void gl_lds16(const void* g, void* l) {
  __builtin_amdgcn_global_load_lds(
      (const __attribute__((address_space(1))) void*)g,
      (__attribute__((address_space(3))) void*)l, 16, 0, 0);
}

__device__ __forceinline__ bf16x8 ldf(const void* p) {
  return __builtin_bit_cast(bf16x8, *(const i32x4*)p);
}

// ---------------- fused f32 -> bf16 convert (one launch) ----------------
__global__ __launch_bounds__(256) void cvt3_kernel(
    const float4* __restrict__ a, ushort4* __restrict__ oa, int na4,
    const float4* __restrict__ b, ushort4* __restrict__ ob, int nb4,
    const float4* __restrict__ c, ushort4* __restrict__ oc, int nc4) {
  const int step = gridDim.x * blockDim.x;
  const int t0 = blockIdx.x * blockDim.x + threadIdx.x;
  for (int i = t0; i < na4; i += step) {
    float4 v = a[i];
    ushort4 o; o.x = f2b(v.x); o.y = f2b(v.y); o.z = f2b(v.z); o.w = f2b(v.w);
    oa[i] = o;
  }
  for (int i = t0; i < nb4; i += step) {
    float4 v = b[i];
    ushort4 o; o.x = f2b(v.x); o.y = f2b(v.y); o.z = f2b(v.z); o.w = f2b(v.w);
    ob[i] = o;
  }
  for (int i = t0; i < nc4; i += step) {
    float4 v = c[i];
    ushort4 o; o.x = f2b(v.x); o.y = f2b(v.y); o.z = f2b(v.z); o.w = f2b(v.w);
    oc[i] = o;
  }
}

// ---------------- GEMM v2: C[m][n] = sum_k A[m][k]*B[n][k] (+bias) ----------------
// 8 waves (512 thr, 2x4 wave grid), BK=64, double-buffered LDS staged via
// global_load_lds (counted vmcnt: next tile's loads stay in flight across
// the barrier — T4). 128B LDS rows XOR-swizzled per rule 21: inverse-swizzle
// the GLOBAL source (gl_lds writes linearly), swizzle the ds_read address.
// EPI=0: QKV scatter epilogue (q/k [bh][t][64], v^T [bh][64][t]); EPI=1: f32 out.
template <int BM, int BN, int EPI>
__global__ __launch_bounds__(512) void gemm2(
    const u16* __restrict__ A, const u16* __restrict__ B,
    const float* __restrict__ bias, int M, int N, int K,
    u16* __restrict__ q_s, u16* __restrict__ k_s, u16* __restrict__ vt_s,
    float* __restrict__ outf) {
  constexpr int MR = BM / 32;   // 16-row frags per wave (wave tile BM/2 rows)
  constexpr int NR = BN / 64;   // 16-col frags per wave (wave tile BN/4 cols)
  constexpr int IA = BM / 64;   // gl_lds issues per wave for A (1KB each)
  constexpr int IB = BN / 64;
  __shared__ __align__(16) u16 As[2][BM * 64];
  __shared__ __align__(16) u16 Bs[2][BN * 64];
  const int tid = threadIdx.x;
  const int w = tid >> 6, l = tid & 63;
  const int lo = l & 15, hi = l >> 4;
  const int wr = w >> 2, wc = w & 3;
  const int bm0 = blockIdx.y * BM, bn0 = blockIdx.x * BN;
  const size_t Kb = (size_t)K * 2;
  const char* Ab = (const char*)A;
  const char* Bb = (const char*)B;
  const int lrow8 = l >> 3;        // row within a 1KB (8x128B) chunk
  const int lcol = (l & 7) * 16;   // 16B slot within the 128B row

  f32x4 acc[MR][NR] = {};

  auto STAGE = [&](int buf, int kt) {
#pragma unroll
    for (int i = 0; i < IA; ++i) {
      int rl = (w * IA + i) * 8 + lrow8;               // local row 0..BM-1
      int cb = lcol ^ ((rl & 7) << 4);                 // inverse-swizzled source
      gl_lds16(Ab + (size_t)(bm0 + rl) * Kb + kt * 128 + cb,
               (char*)&As[buf][0] + (w * IA + i) * 1024);
    }
#pragma unroll
    for (int i = 0; i < IB; ++i) {
      int rl = (w * IB + i) * 8 + lrow8;
      int cb = lcol ^ ((rl & 7) << 4);
      gl_lds16(Bb + (size_t)(bn0 + rl) * Kb + kt * 128 + cb,
               (char*)&Bs[buf][0] + (w * IB + i) * 1024);
    }
  };

  const int nt = K >> 6;
  STAGE(0, 0);
  for (int kt = 0; kt < nt; ++kt) {
    const int cur = kt & 1;
    if (kt + 1 < nt) {
      STAGE(cur ^ 1, kt + 1);  // issue next tile's loads BEFORE waiting
      if constexpr (IA + IB == 8)
        asm volatile("s_waitcnt vmcnt(8)" ::: "memory");   // cur's 8 landed
      else
        asm volatile("s_waitcnt vmcnt(4)" ::: "memory");   // cur's 4 landed
    } else {
      asm volatile("s_waitcnt vmcnt(0)" ::: "memory");
    }
    __builtin_amdgcn_s_barrier();
    __builtin_amdgcn_sched_barrier(0);
    const char* Ap = (const char*)&As[cur][0];
    const char* Bp = (const char*)&Bs[cur][0];
#pragma unroll
    for (int ks = 0; ks < 2; ++ks) {
      bf16x8 bfr[NR];
#pragma unroll
      for (int nf = 0; nf < NR; ++nf) {
        int r = wc * (NR * 16) + nf * 16 + lo;
        bfr[nf] = ldf(Bp + r * 128 + ((ks * 64 + hi * 16) ^ ((r & 7) << 4)));
      }
#pragma unroll
      for (int mf = 0; mf < MR; ++mf) {
        int r = wr * (MR * 16) + mf * 16 + lo;
        bf16x8 afr = ldf(Ap + r * 128 + ((ks * 64 + hi * 16) ^ ((r & 7) << 4)));
#pragma unroll
        for (int nf = 0; nf < NR; ++nf) acc[mf][nf] = MFMA16(afr, bfr[nf], acc[mf][nf]);
      }
    }
    __builtin_amdgcn_sched_barrier(0);
    __builtin_amdgcn_s_barrier();  // all reads of cur done before re-stage
  }

  // Epilogue. C/D layout: col = lo, row = hi*4 + reg (m89/m91-verified).
#pragma unroll
  for (int nf = 0; nf < NR; ++nf) {
    int col = bn0 + wc * (NR * 16) + nf * 16 + lo;
    float bv = bias[col];
    if (EPI == 0) {
      int seg = col / 768;  // 0=q 1=k 2=v (uniform per nf: 16-span never crosses 768)
      int cs = col - seg * 768;
      int h = cs >> 6, d = cs & 63;
      u16* dst = (seg == 0) ? q_s : k_s;
#pragma unroll
      for (int mf = 0; mf < MR; ++mf) {
        int m0 = bm0 + wr * (MR * 16) + mf * 16 + hi * 4;
        int bb = m0 >> 10, t0 = m0 & 1023;
        size_t bh = (size_t)(bb * 12 + h);
        if (seg < 2) {
#pragma unroll
          for (int r = 0; r < 4; ++r)
            dst[(bh * 1024 + t0 + r) * 64 + d] = f2b(acc[mf][nf][r] + bv);
        } else {  // v transposed: 4 consecutive t -> one 8B store
          ushort4 pk;
          pk.x = f2b(acc[mf][nf][0] + bv);
          pk.y = f2b(acc[mf][nf][1] + bv);
          pk.z = f2b(acc[mf][nf][2] + bv);
          pk.w = f2b(acc[mf][nf][3] + bv);
          *(ushort4*)&vt_s[(bh * 64 + d) * 1024 + t0] = pk;
        }
      }
    } else {
#pragma unroll
      for (int mf = 0; mf < MR; ++mf) {
        int m0 = bm0 + wr * (MR * 16) + mf * 16 + hi * 4;
#pragma unroll
        for (int r = 0; r < 4; ++r) outf[(size_t)(m0 + r) * N + col] = acc[mf][nf][r] + bv;
      }
    }
  }
}

// ---------------- causal flash attention, v4 (unchanged) ----------------
__global__ __launch_bounds__(256) void attn_kernel(
    const u16* __restrict__ Q, const u16* __restrict__ Kg,
    const u16* __restrict__ Vt, u16* __restrict__ Y) {
  __shared__ __align__(16) u16 Ks[2][64 * 64];
  __shared__ __align__(16) u16 Vs[2][64 * 64];
  __shared__ __align__(16) u16 Ps[4][16 * 64];
  const int tid = threadIdx.x;
  const int w = tid >> 6, l = tid & 63;
  const int lo = l & 15, hi = l >> 4;
  const int bh = blockIdx.y;
  const int b = bh / 12, h = bh % 12;
  const int pr = blockIdx.x;  // 0..7 -> tiles {pr, 15-pr}
  const float c1 = 0.125f * 1.44269504f;  // scale * log2(e)
  char* pw = (char*)&Ps[w][0];
  const int swl = (lo & 7) << 4;
  const u16* Qb = Q + (size_t)bh * 65536;
  const char* Kbp = (const char*)(Kg + (size_t)bh * 65536);
  const char* Vbp = (const char*)(Vt + (size_t)bh * 65536);  // [64 d][1024 t]

  auto STAGE = [&](int buf, int kb) {
#pragma unroll
    for (int i = 0; i < 2; ++i) {
      int c = w * 2 + i;
      int row = c * 8 + (l >> 3);                    // 8 rows (128B) / chunk
      int cb = ((l & 7) * 16) ^ ((row & 7) << 4);    // inverse-swizzled source
      gl_lds16(Kbp + (size_t)(kb + row) * 128 + cb, (char*)&Ks[buf][0] + c * 1024);
      gl_lds16(Vbp + (size_t)row * 2048 + (size_t)kb * 2 + cb, (char*)&Vs[buf][0] + c * 1024);
    }
  };

  for (int sg = 0; sg < 2; ++sg) {
    const int tile = sg ? (15 - pr) : pr;
    const int q0 = tile * 64 + w * 16;  // wave's 16 q-rows
    const int nt = tile + 1;            // KV tiles of 64

    bf16x8 qf[2];
#pragma unroll
    for (int ks = 0; ks < 2; ++ks)
      qf[ks] = ldf(Qb + (size_t)(q0 + lo) * 64 + ks * 32 + hi * 8);

    f32x4 o[4] = {};
    f32x4 mrow, lrow;
#pragma unroll
    for (int r = 0; r < 4; ++r) { mrow[r] = -1e30f; lrow[r] = 0.0f; }

    STAGE(0, 0);
    for (int kt = 0; kt < nt; ++kt) {
      const int cur = kt & 1;
      if (kt + 1 < nt) {
        STAGE(cur ^ 1, (kt + 1) * 64);
        asm volatile("s_waitcnt vmcnt(4)" ::: "memory");  // prev stage landed
      } else {
        asm volatile("s_waitcnt vmcnt(0)" ::: "memory");
      }
      __builtin_amdgcn_s_barrier();
      __builtin_amdgcn_sched_barrier(0);
      const char* Kt = (const char*)&Ks[cur][0];
      const char* Vv = (const char*)&Vs[cur][0];
      const int kb = kt * 64;

      // ---- QK^T: S[q=row][k=col]
      f32x4 sv[4] = {};
#pragma unroll
      for (int kf = 0; kf < 4; ++kf) {
        int rb = (kf * 16 + lo) * 128;
#pragma unroll
        for (int ks = 0; ks < 2; ++ks)
          sv[kf] = MFMA16(qf[ks], ldf(Kt + rb + ((ks * 64 + hi * 16) ^ swl)), sv[kf]);
      }
      // ---- causal mask (only diagonal tile crosses)
      if (kt == nt - 1) {
#pragma unroll
        for (int kf = 0; kf < 4; ++kf)
#pragma unroll
          for (int r = 0; r < 4; ++r) {
            int qrow = q0 + hi * 4 + r;
            int kcol = kb + kf * 16 + lo;
            if (kcol > qrow) sv[kf][r] = -1e30f;
          }
      }
      // ---- online softmax with defer-max (row = (hi,r); 16 lo-lanes/row)
      f32x4 lm = sv[0];
#pragma unroll
      for (int kf = 1; kf < 4; ++kf)
#pragma unroll
        for (int r = 0; r < 4; ++r) lm[r] = fmaxf(lm[r], sv[kf][r]);
      bool need = false;
#pragma unroll
      for (int r = 0; r < 4; ++r) need |= (lm[r] * c1 > mrow[r] + 8.0f);
      if (__any(need)) {
#pragma unroll
        for (int st = 1; st < 16; st <<= 1)
#pragma unroll
          for (int r = 0; r < 4; ++r) lm[r] = fmaxf(lm[r], __shfl_xor(lm[r], st));
        f32x4 al;
#pragma unroll
        for (int r = 0; r < 4; ++r) {
          float Mn = fmaxf(mrow[r], lm[r] * c1);
          al[r] = __builtin_amdgcn_exp2f(mrow[r] - Mn);
          mrow[r] = Mn;
          lrow[r] *= al[r];
        }
#pragma unroll
        for (int nd = 0; nd < 4; ++nd)
#pragma unroll
          for (int r = 0; r < 4; ++r) o[nd][r] *= al[r];
      }
      f32x4 rs = {0.f, 0.f, 0.f, 0.f};
#pragma unroll
      for (int kf = 0; kf < 4; ++kf)
#pragma unroll
        for (int r = 0; r < 4; ++r) {
          float pv = __builtin_amdgcn_exp2f(fmaf(sv[kf][r], c1, -mrow[r]));
          sv[kf][r] = pv;
          rs[r] += pv;
        }
#pragma unroll
      for (int st = 1; st < 16; st <<= 1)
#pragma unroll
        for (int r = 0; r < 4; ++r) rs[r] += __shfl_xor(rs[r], st);
#pragma unroll
      for (int r = 0; r < 4; ++r) lrow[r] += rs[r];
      // ---- P -> per-wave LDS (swizzled), reload as A-frag
#pragma unroll
      for (int kf = 0; kf < 4; ++kf)
#pragma unroll
        for (int r = 0; r < 4; ++r) {
          int qrow = hi * 4 + r;
          int cb = ((lo + kf * 16) * 2) ^ ((qrow & 7) << 4);
          *(u16*)(pw + qrow * 128 + cb) = f2b(sv[kf][r]);
        }
      bf16x8 pa[2];
#pragma unroll
      for (int ks = 0; ks < 2; ++ks)
        pa[ks] = ldf(pw + lo * 128 + ((ks * 64 + hi * 16) ^ swl));
      // ---- PV: O[q][d] += P[q][k] V[k][d]  (Vs row = d, col = k)
#pragma unroll
      for (int nd = 0; nd < 4; ++nd) {
        int rb = (nd * 16 + lo) * 128;
#pragma unroll
        for (int ks = 0; ks < 2; ++ks)
          o[nd] = MFMA16(pa[ks], ldf(Vv + rb + ((ks * 64 + hi * 16) ^ swl)), o[nd]);
      }
      __builtin_amdgcn_sched_barrier(0);
      __builtin_amdgcn_s_barrier();  // all reads of cur done before re-stage
    }

    // ---- epilogue: y[b][t][h*64+d] bf16
    f32x4 inv;
#pragma unroll
    for (int r = 0; r < 4; ++r) inv[r] = 1.0f / lrow[r];
#pragma unroll
    for (int nd = 0; nd < 4; ++nd)
#pragma unroll
      for (int r = 0; r < 4; ++r) {
        int t = q0 + hi * 4 + r;
        int d = nd * 16 + lo;
        Y[((size_t)b * 1024 + t) * 768 + h * 64 + d] = f2b(o[nd][r] * inv[r]);
      }
  }
}

// ---------------- launcher ----------------
extern "C" void kernel_launch(void* const* d_in, const int* in_sizes, int n_in,
                              void* d_out, int out_size, void* d_ws, size_t ws_size,
                              hipStream_t stream) {
  const float* x  = (const float*)d_in[0];
  const float* Wa = (const float*)d_in[1];
  const float* ba = (const float*)d_in[2];
  const float* Wp = (const float*)d_in[3];
  const float* bp = (const float*)d_in[4];
  float* out = (float*)d_out;
  char* ws = (char*)d_ws;

  constexpr size_t XB  = 0;                       // x bf16   [8192][768]
  constexpr size_t WAB = 12582912;                // W_attn bf16 [2304][768]
  constexpr size_t WPB = WAB + 3538944;           // W_proj bf16 [768][768]
  constexpr size_t QS  = WPB + 1179648;           // q bf16 [96][1024][64]
  constexpr size_t KS  = QS + 12582912;           // k bf16 [96][1024][64]
  constexpr size_t VTS = KS + 12582912;           // v^T bf16 [96][64][1024]
  constexpr size_t YB  = VTS + 12582912;          // y bf16 [8192][768]

  u16* xb  = (u16*)(ws + XB);
  u16* wab = (u16*)(ws + WAB);
  u16* wpb = (u16*)(ws + WPB);
  u16* qs  = (u16*)(ws + QS);
  u16* ks  = (u16*)(ws + KS);
  u16* vts = (u16*)(ws + VTS);
  u16* yb  = (u16*)(ws + YB);

  cvt3_kernel<<<2048, 256, 0, stream>>>(
      (const float4*)x,  (ushort4*)xb,  8192 * 768 / 4,
      (const float4*)Wa, (ushort4*)wab, 2304 * 768 / 4,
      (const float4*)Wp, (ushort4*)wpb, 768 * 768 / 4);

  gemm2<256, 256, 0><<<dim3(9, 32), 512, 0, stream>>>(xb, wab, ba, 8192, 2304, 768,
                                                      qs, ks, vts, nullptr);
  attn_kernel<<<dim3(8, 96), 256, 0, stream>>>(qs, ks, vts, yb);
  gemm2<128, 128, 1><<<dim3(6, 64), 512, 0, stream>>>(yb, wpb, bp, 8192, 768, 768,
                                                      nullptr, nullptr, nullptr, out);
}

// Round 6
// 116.582 us; speedup vs baseline: 1.2370x; 1.2370x over previous
//
#include <hip/hip_runtime.h>

typedef unsigned short u16;
typedef __attribute__((ext_vector_type(8))) __bf16 bf16x8;
typedef __attribute__((ext_vector_type(4))) float f32x4;
typedef __attribute__((ext_vector_type(4))) int i32x4;

#define MFMA16(a, b, c) __builtin_amdgcn_mfma_f32_16x16x32_bf16(a, b, c, 0, 0, 0)

__device__ __forceinline__ u16 f2b(float f) {
  __bf16 h = (__bf16)f;
  return __builtin_bit_cast(u16, h);
}

// global -> LDS direct (wave-uniform LDS base + lane*16; global addr per-lane)
__device__ __forceinline__ void gl_lds16(const void* g, void* l) {
  __builtin_amdgcn_global_load_lds(
      (const __attribute__((address_space(1))) void*)g,
      (__attribute__((address_space(3))) void*)l, 16, 0, 0);
}

__device__ __forceinline__ bf16x8 ldf(const void* p) {
  return __builtin_bit_cast(bf16x8, *(const i32x4*)p);
}

// ---------------- fused f32 -> bf16 convert (one launch) ----------------
__global__ __launch_bounds__(256) void cvt3_kernel(
    const float4* __restrict__ a, ushort4* __restrict__ oa, int na4,
    const float4* __restrict__ b, ushort4* __restrict__ ob, int nb4,
    const float4* __restrict__ c, ushort4* __restrict__ oc, int nc4) {
  const int step = gridDim.x * blockDim.x;
  const int t0 = blockIdx.x * blockDim.x + threadIdx.x;
  for (int i = t0; i < na4; i += step) {
    float4 v = a[i];
    ushort4 o; o.x = f2b(v.x); o.y = f2b(v.y); o.z = f2b(v.z); o.w = f2b(v.w);
    oa[i] = o;
  }
  for (int i = t0; i < nb4; i += step) {
    float4 v = b[i];
    ushort4 o; o.x = f2b(v.x); o.y = f2b(v.y); o.z = f2b(v.z); o.w = f2b(v.w);
    ob[i] = o;
  }
  for (int i = t0; i < nc4; i += step) {
    float4 v = c[i];
    ushort4 o; o.x = f2b(v.x); o.y = f2b(v.y); o.z = f2b(v.z); o.w = f2b(v.w);
    oc[i] = o;
  }
}

// ---------------- GEMM v3: C[m][n] = sum_k A[m][k]*B[n][k] (+bias) ----------------
// BM=128, BN=192, BK=64, 8 waves (2m x 4n), SINGLE-buffered (m97-style:
// __syncthreads drains vmcnt — per-step stall hides under 2-3 co-resident
// blocks/CU). LDS 40 KB; __launch_bounds__(512,4) caps VGPR<=128.
// QKV grid 12x64=768 = 3/CU exact; proj grid 4x64=256 = 1/CU exact.
// 128B LDS rows XOR-swizzled (rule 21: inverse-swizzled global source +
// swizzled ds_read — proven conflict-free in round 5). XCD-aware block
// remap (T1, bijective since grid%8==0).
// EPI=0: QKV scatter epilogue; EPI=1: f32 out.
template <int EPI>
__global__ __launch_bounds__(512, 4) void gemm3(
    const u16* __restrict__ A, const u16* __restrict__ B,
    const float* __restrict__ bias, int M, int N, int K,
    u16* __restrict__ q_s, u16* __restrict__ k_s, u16* __restrict__ vt_s,
    float* __restrict__ outf) {
  constexpr int BM = 128, BN = 192;
  constexpr int NR = BN / 64;   // 3 col-frags per wave (wave tile 64x48)
  constexpr int IA = BM / 64;   // 2 gl_lds issues per wave for A
  constexpr int IB = BN / 64;   // 3 for B
  __shared__ __align__(16) u16 As[BM * 64];  // 16 KB
  __shared__ __align__(16) u16 Bs[BN * 64];  // 24 KB
  const int tid = threadIdx.x;
  const int w = tid >> 6, l = tid & 63;
  const int lo = l & 15, hi = l >> 4;
  const int wr = w >> 2, wc = w & 3;
  // XCD-aware bijective remap (grid is a multiple of 8)
  const int nwg = gridDim.x * gridDim.y;
  int bid = blockIdx.y * gridDim.x + blockIdx.x;
  bid = (bid & 7) * (nwg >> 3) + (bid >> 3);
  const int bm0 = (bid / gridDim.x) * BM;
  const int bn0 = (bid % gridDim.x) * BN;
  const size_t Kb = (size_t)K * 2;
  const char* Ab = (const char*)A;
  const char* Bb = (const char*)B;
  const int lrow8 = l >> 3;        // row within a 1KB (8x128B) chunk
  const int lcol = (l & 7) * 16;   // 16B slot within the 128B row

  f32x4 acc[4][NR] = {};

  for (int kt = 0; kt < K; kt += 64) {
    __syncthreads();  // prior reads of As/Bs done before overwrite
#pragma unroll
    for (int i = 0; i < IA; ++i) {
      int rl = (w * IA + i) * 8 + lrow8;
      int cb = lcol ^ ((rl & 7) << 4);  // inverse-swizzled source
      gl_lds16(Ab + (size_t)(bm0 + rl) * Kb + kt * 2 + cb,
               (char*)As + (w * IA + i) * 1024);
    }
#pragma unroll
    for (int i = 0; i < IB; ++i) {
      int rl = (w * IB + i) * 8 + lrow8;
      int cb = lcol ^ ((rl & 7) << 4);
      gl_lds16(Bb + (size_t)(bn0 + rl) * Kb + kt * 2 + cb,
               (char*)Bs + (w * IB + i) * 1024);
    }
    __syncthreads();  // compiler drains vmcnt(0) before barrier -> tile ready
#pragma unroll
    for (int ks = 0; ks < 2; ++ks) {
      bf16x8 bfr[NR];
#pragma unroll
      for (int nf = 0; nf < NR; ++nf) {
        int r = wc * (NR * 16) + nf * 16 + lo;
        bfr[nf] = ldf((char*)Bs + r * 128 + ((ks * 64 + hi * 16) ^ ((r & 7) << 4)));
      }
#pragma unroll
      for (int mf = 0; mf < 4; ++mf) {
        int r = wr * 64 + mf * 16 + lo;
        bf16x8 afr = ldf((char*)As + r * 128 + ((ks * 64 + hi * 16) ^ ((r & 7) << 4)));
#pragma unroll
        for (int nf = 0; nf < NR; ++nf) acc[mf][nf] = MFMA16(afr, bfr[nf], acc[mf][nf]);
      }
    }
  }

  // Epilogue. C/D layout: col = lo, row = hi*4 + reg (m89/m91-verified).
#pragma unroll
  for (int nf = 0; nf < NR; ++nf) {
    int col = bn0 + wc * (NR * 16) + nf * 16 + lo;
    float bv = bias[col];
    if (EPI == 0) {
      int seg = col / 768;  // 0=q 1=k 2=v (BN=192 divides 768: uniform per block)
      int cs = col - seg * 768;
      int h = cs >> 6, d = cs & 63;
      u16* dst = (seg == 0) ? q_s : k_s;
#pragma unroll
      for (int mf = 0; mf < 4; ++mf) {
        int m0 = bm0 + wr * 64 + mf * 16 + hi * 4;
        int bb = m0 >> 10, t0 = m0 & 1023;
        size_t bh = (size_t)(bb * 12 + h);
        if (seg < 2) {
#pragma unroll
          for (int r = 0; r < 4; ++r)
            dst[(bh * 1024 + t0 + r) * 64 + d] = f2b(acc[mf][nf][r] + bv);
        } else {  // v transposed: 4 consecutive t -> one 8B store
          ushort4 pk;
          pk.x = f2b(acc[mf][nf][0] + bv);
          pk.y = f2b(acc[mf][nf][1] + bv);
          pk.z = f2b(acc[mf][nf][2] + bv);
          pk.w = f2b(acc[mf][nf][3] + bv);
          *(ushort4*)&vt_s[(bh * 64 + d) * 1024 + t0] = pk;
        }
      }
    } else {
#pragma unroll
      for (int mf = 0; mf < 4; ++mf) {
        int m0 = bm0 + wr * 64 + mf * 16 + hi * 4;
#pragma unroll
        for (int r = 0; r < 4; ++r) outf[(size_t)(m0 + r) * N + col] = acc[mf][nf][r] + bv;
      }
    }
  }
}

// ---------------- causal flash attention, v4 + XCD remap ----------------
__global__ __launch_bounds__(256) void attn_kernel(
    const u16* __restrict__ Q, const u16* __restrict__ Kg,
    const u16* __restrict__ Vt, u16* __restrict__ Y) {
  __shared__ __align__(16) u16 Ks[2][64 * 64];
  __shared__ __align__(16) u16 Vs[2][64 * 64];
  __shared__ __align__(16) u16 Ps[4][16 * 64];
  const int tid = threadIdx.x;
  const int w = tid >> 6, l = tid & 63;
  const int lo = l & 15, hi = l >> 4;
  // XCD-aware bijective remap (768 blocks % 8 == 0): same-bh blocks -> same XCD
  int bid = blockIdx.y * gridDim.x + blockIdx.x;
  bid = (bid & 7) * 96 + (bid >> 3);
  const int bh = bid >> 3;
  const int pr = bid & 7;  // 0..7 -> tiles {pr, 15-pr}
  const int b = bh / 12, h = bh % 12;
  const float c1 = 0.125f * 1.44269504f;  // scale * log2(e)
  char* pw = (char*)&Ps[w][0];
  const int swl = (lo & 7) << 4;
  const u16* Qb = Q + (size_t)bh * 65536;
  const char* Kbp = (const char*)(Kg + (size_t)bh * 65536);
  const char* Vbp = (const char*)(Vt + (size_t)bh * 65536);  // [64 d][1024 t]

  auto STAGE = [&](int buf, int kb) {
#pragma unroll
    for (int i = 0; i < 2; ++i) {
      int c = w * 2 + i;
      int row = c * 8 + (l >> 3);                    // 8 rows (128B) / chunk
      int cb = ((l & 7) * 16) ^ ((row & 7) << 4);    // inverse-swizzled source
      gl_lds16(Kbp + (size_t)(kb + row) * 128 + cb, (char*)&Ks[buf][0] + c * 1024);
      gl_lds16(Vbp + (size_t)row * 2048 + (size_t)kb * 2 + cb, (char*)&Vs[buf][0] + c * 1024);
    }
  };

  for (int sg = 0; sg < 2; ++sg) {
    const int tile = sg ? (15 - pr) : pr;
    const int q0 = tile * 64 + w * 16;  // wave's 16 q-rows
    const int nt = tile + 1;            // KV tiles of 64

    bf16x8 qf[2];
#pragma unroll
    for (int ks = 0; ks < 2; ++ks)
      qf[ks] = ldf(Qb + (size_t)(q0 + lo) * 64 + ks * 32 + hi * 8);

    f32x4 o[4] = {};
    f32x4 mrow, lrow;
#pragma unroll
    for (int r = 0; r < 4; ++r) { mrow[r] = -1e30f; lrow[r] = 0.0f; }

    STAGE(0, 0);
    for (int kt = 0; kt < nt; ++kt) {
      const int cur = kt & 1;
      if (kt + 1 < nt) {
        STAGE(cur ^ 1, (kt + 1) * 64);
        asm volatile("s_waitcnt vmcnt(4)" ::: "memory");  // prev stage landed
      } else {
        asm volatile("s_waitcnt vmcnt(0)" ::: "memory");
      }
      __builtin_amdgcn_s_barrier();
      __builtin_amdgcn_sched_barrier(0);
      const char* Kt = (const char*)&Ks[cur][0];
      const char* Vv = (const char*)&Vs[cur][0];
      const int kb = kt * 64;

      // ---- QK^T: S[q=row][k=col]
      f32x4 sv[4] = {};
#pragma unroll
      for (int kf = 0; kf < 4; ++kf) {
        int rb = (kf * 16 + lo) * 128;
#pragma unroll
        for (int ks = 0; ks < 2; ++ks)
          sv[kf] = MFMA16(qf[ks], ldf(Kt + rb + ((ks * 64 + hi * 16) ^ swl)), sv[kf]);
      }
      // ---- causal mask (only diagonal tile crosses)
      if (kt == nt - 1) {
#pragma unroll
        for (int kf = 0; kf < 4; ++kf)
#pragma unroll
          for (int r = 0; r < 4; ++r) {
            int qrow = q0 + hi * 4 + r;
            int kcol = kb + kf * 16 + lo;
            if (kcol > qrow) sv[kf][r] = -1e30f;
          }
      }
      // ---- online softmax with defer-max (row = (hi,r); 16 lo-lanes/row)
      f32x4 lm = sv[0];
#pragma unroll
      for (int kf = 1; kf < 4; ++kf)
#pragma unroll
        for (int r = 0; r < 4; ++r) lm[r] = fmaxf(lm[r], sv[kf][r]);
      bool need = false;
#pragma unroll
      for (int r = 0; r < 4; ++r) need |= (lm[r] * c1 > mrow[r] + 8.0f);
      if (__any(need)) {
#pragma unroll
        for (int st = 1; st < 16; st <<= 1)
#pragma unroll
          for (int r = 0; r < 4; ++r) lm[r] = fmaxf(lm[r], __shfl_xor(lm[r], st));
        f32x4 al;
#pragma unroll
        for (int r = 0; r < 4; ++r) {
          float Mn = fmaxf(mrow[r], lm[r] * c1);
          al[r] = __builtin_amdgcn_exp2f(mrow[r] - Mn);
          mrow[r] = Mn;
          lrow[r] *= al[r];
        }
#pragma unroll
        for (int nd = 0; nd < 4; ++nd)
#pragma unroll
          for (int r = 0; r < 4; ++r) o[nd][r] *= al[r];
      }
      f32x4 rs = {0.f, 0.f, 0.f, 0.f};
#pragma unroll
      for (int kf = 0; kf < 4; ++kf)
#pragma unroll
        for (int r = 0; r < 4; ++r) {
          float pv = __builtin_amdgcn_exp2f(fmaf(sv[kf][r], c1, -mrow[r]));
          sv[kf][r] = pv;
          rs[r] += pv;
        }
#pragma unroll
      for (int st = 1; st < 16; st <<= 1)
#pragma unroll
        for (int r = 0; r < 4; ++r) rs[r] += __shfl_xor(rs[r], st);
#pragma unroll
      for (int r = 0; r < 4; ++r) lrow[r] += rs[r];
      // ---- P -> per-wave LDS (swizzled), reload as A-frag
#pragma unroll
      for (int kf = 0; kf < 4; ++kf)
#pragma unroll
        for (int r = 0; r < 4; ++r) {
          int qrow = hi * 4 + r;
          int cb = ((lo + kf * 16) * 2) ^ ((qrow & 7) << 4);
          *(u16*)(pw + qrow * 128 + cb) = f2b(sv[kf][r]);
        }
      bf16x8 pa[2];
#pragma unroll
      for (int ks = 0; ks < 2; ++ks)
        pa[ks] = ldf(pw + lo * 128 + ((ks * 64 + hi * 16) ^ swl));
      // ---- PV: O[q][d] += P[q][k] V[k][d]  (Vs row = d, col = k)
#pragma unroll
      for (int nd = 0; nd < 4; ++nd) {
        int rb = (nd * 16 + lo) * 128;
#pragma unroll
        for (int ks = 0; ks < 2; ++ks)
          o[nd] = MFMA16(pa[ks], ldf(Vv + rb + ((ks * 64 + hi * 16) ^ swl)), o[nd]);
      }
      __builtin_amdgcn_sched_barrier(0);
      __builtin_amdgcn_s_barrier();  // all reads of cur done before re-stage
    }

    // ---- epilogue: y[b][t][h*64+d] bf16
    f32x4 inv;
#pragma unroll
    for (int r = 0; r < 4; ++r) inv[r] = 1.0f / lrow[r];
#pragma unroll
    for (int nd = 0; nd < 4; ++nd)
#pragma unroll
      for (int r = 0; r < 4; ++r) {
        int t = q0 + hi * 4 + r;
        int d = nd * 16 + lo;
        Y[((size_t)b * 1024 + t) * 768 + h * 64 + d] = f2b(o[nd][r] * inv[r]);
      }
  }
}

// ---------------- launcher ----------------
extern "C" void kernel_launch(void* const* d_in, const int* in_sizes, int n_in,
                              void* d_out, int out_size, void* d_ws, size_t ws_size,
                              hipStream_t stream) {
  const float* x  = (const float*)d_in[0];
  const float* Wa = (const float*)d_in[1];
  const float* ba = (const float*)d_in[2];
  const float* Wp = (const float*)d_in[3];
  const float* bp = (const float*)d_in[4];
  float* out = (float*)d_out;
  char* ws = (char*)d_ws;

  constexpr size_t XB  = 0;                       // x bf16   [8192][768]
  constexpr size_t WAB = 12582912;                // W_attn bf16 [2304][768]
  constexpr size_t WPB = WAB + 3538944;           // W_proj bf16 [768][768]
  constexpr size_t QS  = WPB + 1179648;           // q bf16 [96][1024][64]
  constexpr size_t KS  = QS + 12582912;           // k bf16 [96][1024][64]
  constexpr size_t VTS = KS + 12582912;           // v^T bf16 [96][64][1024]
  constexpr size_t YB  = VTS + 12582912;          // y bf16 [8192][768]

  u16* xb  = (u16*)(ws + XB);
  u16* wab = (u16*)(ws + WAB);
  u16* wpb = (u16*)(ws + WPB);
  u16* qs  = (u16*)(ws + QS);
  u16* ks  = (u16*)(ws + KS);
  u16* vts = (u16*)(ws + VTS);
  u16* yb  = (u16*)(ws + YB);

  cvt3_kernel<<<2048, 256, 0, stream>>>(
      (const float4*)x,  (ushort4*)xb,  8192 * 768 / 4,
      (const float4*)Wa, (ushort4*)wab, 2304 * 768 / 4,
      (const float4*)Wp, (ushort4*)wpb, 768 * 768 / 4);

  gemm3<0><<<dim3(12, 64), 512, 0, stream>>>(xb, wab, ba, 8192, 2304, 768,
                                             qs, ks, vts, nullptr);
  attn_kernel<<<dim3(8, 96), 256, 0, stream>>>(qs, ks, vts, yb);
  gemm3<1><<<dim3(4, 64), 512, 0, stream>>>(yb, wpb, bp, 8192, 768, 768,
                                            nullptr, nullptr, nullptr, out);
}

// Round 7
// 105.745 us; speedup vs baseline: 1.3638x; 1.1025x over previous
//
#include <hip/hip_runtime.h>

typedef unsigned short u16;
typedef __attribute__((ext_vector_type(8))) __bf16 bf16x8;
typedef __attribute__((ext_vector_type(4))) float f32x4;
typedef __attribute__((ext_vector_type(4))) int i32x4;

#define MFMA16(a, b, c) __builtin_amdgcn_mfma_f32_16x16x32_bf16(a, b, c, 0, 0, 0)

__device__ __forceinline__ u16 f2b(float f) {
  __bf16 h = (__bf16)f;
  return __builtin_bit_cast(u16, h);
}

// global -> LDS direct (wave-uniform LDS base + lane*16; global addr per-lane)
__device__ __forceinline__ void gl_lds16(const void* g, void* l) {
  __builtin_amdgcn_global_load_lds(
      (const __attribute__((address_space(1))) void*)g,
      (__attribute__((address_space(3))) void*)l, 16, 0, 0);
}

__device__ __forceinline__ bf16x8 ldf(const void* p) {
  return __builtin_bit_cast(bf16x8, *(const i32x4*)p);
}

// ---------------- fused f32 -> bf16 convert (one launch) ----------------
__global__ __launch_bounds__(256) void cvt3_kernel(
    const float4* __restrict__ a, ushort4* __restrict__ oa, int na4,
    const float4* __restrict__ b, ushort4* __restrict__ ob, int nb4,
    const float4* __restrict__ c, ushort4* __restrict__ oc, int nc4) {
  const int step = gridDim.x * blockDim.x;
  const int t0 = blockIdx.x * blockDim.x + threadIdx.x;
  for (int i = t0; i < na4; i += step) {
    float4 v = a[i];
    ushort4 o; o.x = f2b(v.x); o.y = f2b(v.y); o.z = f2b(v.z); o.w = f2b(v.w);
    oa[i] = o;
  }
  for (int i = t0; i < nb4; i += step) {
    float4 v = b[i];
    ushort4 o; o.x = f2b(v.x); o.y = f2b(v.y); o.z = f2b(v.z); o.w = f2b(v.w);
    ob[i] = o;
  }
  for (int i = t0; i < nc4; i += step) {
    float4 v = c[i];
    ushort4 o; o.x = f2b(v.x); o.y = f2b(v.y); o.z = f2b(v.z); o.w = f2b(v.w);
    oc[i] = o;
  }
}

// ---------------- GEMM v3: C[m][n] = sum_k A[m][k]*B[n][k] (+bias) ----------------
// BM templated (128 QKV / 64 proj), BN=192, BK=64, 8 waves (2m x 4n),
// single-buffered (syncthreads drains vmcnt; per-step stall hides under
// 2-3 co-resident blocks/CU). 128B LDS rows XOR-swizzled (rule 21:
// inverse-swizzled global source + swizzled ds_read — conflict-free,
// round-5-verified). XCD-aware bijective block remap (grid%8==0).
// EPI=0: QKV scatter epilogue; EPI=1: f32 out.
template <int BM, int EPI>
__global__ __launch_bounds__(512, 4) void gemm3(
    const u16* __restrict__ A, const u16* __restrict__ B,
    const float* __restrict__ bias, int M, int N, int K,
    u16* __restrict__ q_s, u16* __restrict__ k_s, u16* __restrict__ vt_s,
    float* __restrict__ outf) {
  constexpr int BN = 192;
  constexpr int MR = BM / 32;   // 16-row frags per wave (wave tile BM/2 rows)
  constexpr int NR = BN / 64;   // 3 col-frags per wave (wave tile 64x48)
  constexpr int IA = BM / 64;   // gl_lds issues per wave for A
  constexpr int IB = BN / 64;   // 3 for B
  __shared__ __align__(16) u16 As[BM * 64];
  __shared__ __align__(16) u16 Bs[BN * 64];  // 24 KB
  const int tid = threadIdx.x;
  const int w = tid >> 6, l = tid & 63;
  const int lo = l & 15, hi = l >> 4;
  const int wr = w >> 2, wc = w & 3;
  // XCD-aware bijective remap (grid is a multiple of 8)
  const int nwg = gridDim.x * gridDim.y;
  int bid = blockIdx.y * gridDim.x + blockIdx.x;
  bid = (bid & 7) * (nwg >> 3) + (bid >> 3);
  const int bm0 = (bid / gridDim.x) * BM;
  const int bn0 = (bid % gridDim.x) * BN;
  const size_t Kb = (size_t)K * 2;
  const char* Ab = (const char*)A;
  const char* Bb = (const char*)B;
  const int lrow8 = l >> 3;        // row within a 1KB (8x128B) chunk
  const int lcol = (l & 7) * 16;   // 16B slot within the 128B row

  f32x4 acc[MR][NR] = {};

  for (int kt = 0; kt < K; kt += 64) {
    __syncthreads();  // prior reads of As/Bs done before overwrite
#pragma unroll
    for (int i = 0; i < IA; ++i) {
      int rl = (w * IA + i) * 8 + lrow8;
      int cb = lcol ^ ((rl & 7) << 4);  // inverse-swizzled source
      gl_lds16(Ab + (size_t)(bm0 + rl) * Kb + kt * 2 + cb,
               (char*)As + (w * IA + i) * 1024);
    }
#pragma unroll
    for (int i = 0; i < IB; ++i) {
      int rl = (w * IB + i) * 8 + lrow8;
      int cb = lcol ^ ((rl & 7) << 4);
      gl_lds16(Bb + (size_t)(bn0 + rl) * Kb + kt * 2 + cb,
               (char*)Bs + (w * IB + i) * 1024);
    }
    __syncthreads();  // compiler drains vmcnt(0) before barrier -> tile ready
#pragma unroll
    for (int ks = 0; ks < 2; ++ks) {
      bf16x8 bfr[NR];
#pragma unroll
      for (int nf = 0; nf < NR; ++nf) {
        int r = wc * (NR * 16) + nf * 16 + lo;
        bfr[nf] = ldf((char*)Bs + r * 128 + ((ks * 64 + hi * 16) ^ ((r & 7) << 4)));
      }
#pragma unroll
      for (int mf = 0; mf < MR; ++mf) {
        int r = wr * (MR * 16) + mf * 16 + lo;
        bf16x8 afr = ldf((char*)As + r * 128 + ((ks * 64 + hi * 16) ^ ((r & 7) << 4)));
#pragma unroll
        for (int nf = 0; nf < NR; ++nf) acc[mf][nf] = MFMA16(afr, bfr[nf], acc[mf][nf]);
      }
    }
  }

  // Epilogue. C/D layout: col = lo, row = hi*4 + reg (m89/m91-verified).
#pragma unroll
  for (int nf = 0; nf < NR; ++nf) {
    int col = bn0 + wc * (NR * 16) + nf * 16 + lo;
    float bv = bias[col];
    if (EPI == 0) {
      int seg = col / 768;  // 0=q 1=k 2=v (BN=192 divides 768: uniform per block)
      int cs = col - seg * 768;
      int h = cs >> 6, d = cs & 63;
      u16* dst = (seg == 0) ? q_s : k_s;
#pragma unroll
      for (int mf = 0; mf < MR; ++mf) {
        int m0 = bm0 + wr * (MR * 16) + mf * 16 + hi * 4;
        int bb = m0 >> 10, t0 = m0 & 1023;
        size_t bh = (size_t)(bb * 12 + h);
        if (seg < 2) {
#pragma unroll
          for (int r = 0; r < 4; ++r)
            dst[(bh * 1024 + t0 + r) * 64 + d] = f2b(acc[mf][nf][r] + bv);
        } else {  // v transposed: 4 consecutive t -> one 8B store
          ushort4 pk;
          pk.x = f2b(acc[mf][nf][0] + bv);
          pk.y = f2b(acc[mf][nf][1] + bv);
          pk.z = f2b(acc[mf][nf][2] + bv);
          pk.w = f2b(acc[mf][nf][3] + bv);
          *(ushort4*)&vt_s[(bh * 64 + d) * 1024 + t0] = pk;
        }
      }
    } else {
#pragma unroll
      for (int mf = 0; mf < MR; ++mf) {
        int m0 = bm0 + wr * (MR * 16) + mf * 16 + hi * 4;
#pragma unroll
        for (int r = 0; r < 4; ++r) outf[(size_t)(m0 + r) * N + col] = acc[mf][nf][r] + bv;
      }
    }
  }
}

// ---------------- causal flash attention, v5 ----------------
// v4 + (a) rowsum via ones-MFMA (kills the 4-stage shfl sum-tree on the
// per-tile critical path; matrix pipe was 11% busy), (b) V LDS->reg reads
// hoisted above softmax (lgkm latency hides under VALU), (c) T5 setprio
// around MFMA clusters. Structure/balance/swizzle unchanged from v4.
__global__ __launch_bounds__(256) void attn_kernel(
    const u16* __restrict__ Q, const u16* __restrict__ Kg,
    const u16* __restrict__ Vt, u16* __restrict__ Y) {
  __shared__ __align__(16) u16 Ks[2][64 * 64];
  __shared__ __align__(16) u16 Vs[2][64 * 64];
  __shared__ __align__(16) u16 Ps[4][16 * 64];
  const int tid = threadIdx.x;
  const int w = tid >> 6, l = tid & 63;
  const int lo = l & 15, hi = l >> 4;
  // XCD-aware bijective remap (768 blocks % 8 == 0): same-bh blocks -> same XCD
  int bid = blockIdx.y * gridDim.x + blockIdx.x;
  bid = (bid & 7) * 96 + (bid >> 3);
  const int bh = bid >> 3;
  const int pr = bid & 7;  // 0..7 -> tiles {pr, 15-pr}
  const int b = bh / 12, h = bh % 12;
  const float c1 = 0.125f * 1.44269504f;  // scale * log2(e)
  char* pw = (char*)&Ps[w][0];
  const int swl = (lo & 7) << 4;
  const u16* Qb = Q + (size_t)bh * 65536;
  const char* Kbp = (const char*)(Kg + (size_t)bh * 65536);
  const char* Vbp = (const char*)(Vt + (size_t)bh * 65536);  // [64 d][1024 t]

  bf16x8 onesv;
#pragma unroll
  for (int j = 0; j < 8; ++j) onesv[j] = (__bf16)1.0f;

  auto STAGE = [&](int buf, int kb) {
#pragma unroll
    for (int i = 0; i < 2; ++i) {
      int c = w * 2 + i;
      int row = c * 8 + (l >> 3);                    // 8 rows (128B) / chunk
      int cb = ((l & 7) * 16) ^ ((row & 7) << 4);    // inverse-swizzled source
      gl_lds16(Kbp + (size_t)(kb + row) * 128 + cb, (char*)&Ks[buf][0] + c * 1024);
      gl_lds16(Vbp + (size_t)row * 2048 + (size_t)kb * 2 + cb, (char*)&Vs[buf][0] + c * 1024);
    }
  };

  for (int sg = 0; sg < 2; ++sg) {
    const int tile = sg ? (15 - pr) : pr;
    const int q0 = tile * 64 + w * 16;  // wave's 16 q-rows
    const int nt = tile + 1;            // KV tiles of 64

    bf16x8 qf[2];
#pragma unroll
    for (int ks = 0; ks < 2; ++ks)
      qf[ks] = ldf(Qb + (size_t)(q0 + lo) * 64 + ks * 32 + hi * 8);

    f32x4 o[4] = {};
    f32x4 mrow, lsum;
#pragma unroll
    for (int r = 0; r < 4; ++r) { mrow[r] = -1e30f; lsum[r] = 0.0f; }

    STAGE(0, 0);
    for (int kt = 0; kt < nt; ++kt) {
      const int cur = kt & 1;
      if (kt + 1 < nt) {
        STAGE(cur ^ 1, (kt + 1) * 64);
        asm volatile("s_waitcnt vmcnt(4)" ::: "memory");  // prev stage landed
      } else {
        asm volatile("s_waitcnt vmcnt(0)" ::: "memory");
      }
      __builtin_amdgcn_s_barrier();
      __builtin_amdgcn_sched_barrier(0);
      const char* Kt = (const char*)&Ks[cur][0];
      const char* Vv = (const char*)&Vs[cur][0];
      const int kb = kt * 64;

      // ---- QK^T: S[q=row][k=col]
      f32x4 sv[4] = {};
      __builtin_amdgcn_s_setprio(1);
#pragma unroll
      for (int kf = 0; kf < 4; ++kf) {
        int rb = (kf * 16 + lo) * 128;
#pragma unroll
        for (int ks = 0; ks < 2; ++ks)
          sv[kf] = MFMA16(qf[ks], ldf(Kt + rb + ((ks * 64 + hi * 16) ^ swl)), sv[kf]);
      }
      __builtin_amdgcn_s_setprio(0);
      // ---- V frags hoisted: lgkm latency hides under softmax VALU
      bf16x8 vb[4][2];
#pragma unroll
      for (int nd = 0; nd < 4; ++nd) {
        int rb = (nd * 16 + lo) * 128;
#pragma unroll
        for (int ks = 0; ks < 2; ++ks)
          vb[nd][ks] = ldf(Vv + rb + ((ks * 64 + hi * 16) ^ swl));
      }
      // ---- causal mask (only diagonal tile crosses)
      if (kt == nt - 1) {
#pragma unroll
        for (int kf = 0; kf < 4; ++kf)
#pragma unroll
          for (int r = 0; r < 4; ++r) {
            int qrow = q0 + hi * 4 + r;
            int kcol = kb + kf * 16 + lo;
            if (kcol > qrow) sv[kf][r] = -1e30f;
          }
      }
      // ---- online softmax with defer-max (row = (hi,r); 16 lo-lanes/row)
      f32x4 lm = sv[0];
#pragma unroll
      for (int kf = 1; kf < 4; ++kf)
#pragma unroll
        for (int r = 0; r < 4; ++r) lm[r] = fmaxf(lm[r], sv[kf][r]);
      bool need = false;
#pragma unroll
      for (int r = 0; r < 4; ++r) need |= (lm[r] * c1 > mrow[r] + 8.0f);
      if (__any(need)) {
#pragma unroll
        for (int st = 1; st < 16; st <<= 1)
#pragma unroll
          for (int r = 0; r < 4; ++r) lm[r] = fmaxf(lm[r], __shfl_xor(lm[r], st));
        f32x4 al;
#pragma unroll
        for (int r = 0; r < 4; ++r) {
          float Mn = fmaxf(mrow[r], lm[r] * c1);
          al[r] = __builtin_amdgcn_exp2f(mrow[r] - Mn);
          mrow[r] = Mn;
          lsum[r] *= al[r];
        }
#pragma unroll
        for (int nd = 0; nd < 4; ++nd)
#pragma unroll
          for (int r = 0; r < 4; ++r) o[nd][r] *= al[r];
      }
      // P = exp2(S*c1 - m); rowsum comes from the ones-MFMA below.
#pragma unroll
      for (int kf = 0; kf < 4; ++kf)
#pragma unroll
        for (int r = 0; r < 4; ++r)
          sv[kf][r] = __builtin_amdgcn_exp2f(fmaf(sv[kf][r], c1, -mrow[r]));
      // ---- P -> per-wave LDS (swizzled), reload as A-frag
#pragma unroll
      for (int kf = 0; kf < 4; ++kf)
#pragma unroll
        for (int r = 0; r < 4; ++r) {
          int qrow = hi * 4 + r;
          int cb = ((lo + kf * 16) * 2) ^ ((qrow & 7) << 4);
          *(u16*)(pw + qrow * 128 + cb) = f2b(sv[kf][r]);
        }
      bf16x8 pa[2];
#pragma unroll
      for (int ks = 0; ks < 2; ++ks)
        pa[ks] = ldf(pw + lo * 128 + ((ks * 64 + hi * 16) ^ swl));
      // ---- PV: O[q][d] += P[q][k] V[k][d]; rowsum l += P·1 (ones-MFMA)
      __builtin_amdgcn_s_setprio(1);
#pragma unroll
      for (int ks = 0; ks < 2; ++ks) {
#pragma unroll
        for (int nd = 0; nd < 4; ++nd) o[nd] = MFMA16(pa[ks], vb[nd][ks], o[nd]);
        lsum = MFMA16(pa[ks], onesv, lsum);
      }
      __builtin_amdgcn_s_setprio(0);
      __builtin_amdgcn_sched_barrier(0);
      __builtin_amdgcn_s_barrier();  // all reads of cur done before re-stage
    }

    // ---- epilogue: y[b][t][h*64+d] bf16
    f32x4 inv;
#pragma unroll
    for (int r = 0; r < 4; ++r) inv[r] = 1.0f / lsum[r];
#pragma unroll
    for (int nd = 0; nd < 4; ++nd)
#pragma unroll
      for (int r = 0; r < 4; ++r) {
        int t = q0 + hi * 4 + r;
        int d = nd * 16 + lo;
        Y[((size_t)b * 1024 + t) * 768 + h * 64 + d] = f2b(o[nd][r] * inv[r]);
      }
  }
}

// ---------------- launcher ----------------
extern "C" void kernel_launch(void* const* d_in, const int* in_sizes, int n_in,
                              void* d_out, int out_size, void* d_ws, size_t ws_size,
                              hipStream_t stream) {
  const float* x  = (const float*)d_in[0];
  const float* Wa = (const float*)d_in[1];
  const float* ba = (const float*)d_in[2];
  const float* Wp = (const float*)d_in[3];
  const float* bp = (const float*)d_in[4];
  float* out = (float*)d_out;
  char* ws = (char*)d_ws;

  constexpr size_t XB  = 0;                       // x bf16   [8192][768]
  constexpr size_t WAB = 12582912;                // W_attn bf16 [2304][768]
  constexpr size_t WPB = WAB + 3538944;           // W_proj bf16 [768][768]
  constexpr size_t QS  = WPB + 1179648;           // q bf16 [96][1024][64]
  constexpr size_t KS  = QS + 12582912;           // k bf16 [96][1024][64]
  constexpr size_t VTS = KS + 12582912;           // v^T bf16 [96][64][1024]
  constexpr size_t YB  = VTS + 12582912;          // y bf16 [8192][768]

  u16* xb  = (u16*)(ws + XB);
  u16* wab = (u16*)(ws + WAB);
  u16* wpb = (u16*)(ws + WPB);
  u16* qs  = (u16*)(ws + QS);
  u16* ks  = (u16*)(ws + KS);
  u16* vts = (u16*)(ws + VTS);
  u16* yb  = (u16*)(ws + YB);

  cvt3_kernel<<<2048, 256, 0, stream>>>(
      (const float4*)x,  (ushort4*)xb,  8192 * 768 / 4,
      (const float4*)Wa, (ushort4*)wab, 2304 * 768 / 4,
      (const float4*)Wp, (ushort4*)wpb, 768 * 768 / 4);

  gemm3<128, 0><<<dim3(12, 64), 512, 0, stream>>>(xb, wab, ba, 8192, 2304, 768,
                                                  qs, ks, vts, nullptr);
  attn_kernel<<<dim3(8, 96), 256, 0, stream>>>(qs, ks, vts, yb);
  gemm3<64, 1><<<dim3(4, 128), 512, 0, stream>>>(yb, wpb, bp, 8192, 768, 768,
                                                 nullptr, nullptr, nullptr, out);
}

// Round 8
// 99.840 us; speedup vs baseline: 1.4444x; 1.0591x over previous
//
#include <hip/hip_runtime.h>

typedef unsigned short u16;
typedef __attribute__((ext_vector_type(8))) __bf16 bf16x8;
typedef __attribute__((ext_vector_type(4))) float f32x4;
typedef __attribute__((ext_vector_type(4))) int i32x4;

#define MFMA16(a, b, c) __builtin_amdgcn_mfma_f32_16x16x32_bf16(a, b, c, 0, 0, 0)

__device__ __forceinline__ u16 f2b(float f) {
  __bf16 h = (__bf16)f;
  return __builtin_bit_cast(u16, h);
}

// global -> LDS direct (wave-uniform LDS base + lane*16; global addr per-lane)
__device__ __forceinline__ void gl_lds16(const void* g, void* l) {
  __builtin_amdgcn_global_load_lds(
      (const __attribute__((address_space(1))) void*)g,
      (__attribute__((address_space(3))) void*)l, 16, 0, 0);
}

__device__ __forceinline__ bf16x8 ldf(const void* p) {
  return __builtin_bit_cast(bf16x8, *(const i32x4*)p);
}

// ---------------- fused f32 -> bf16 convert (one launch) ----------------
__global__ __launch_bounds__(256) void cvt3_kernel(
    const float4* __restrict__ a, ushort4* __restrict__ oa, int na4,
    const float4* __restrict__ b, ushort4* __restrict__ ob, int nb4,
    const float4* __restrict__ c, ushort4* __restrict__ oc, int nc4) {
  const int step = gridDim.x * blockDim.x;
  const int t0 = blockIdx.x * blockDim.x + threadIdx.x;
  for (int i = t0; i < na4; i += step) {
    float4 v = a[i];
    ushort4 o; o.x = f2b(v.x); o.y = f2b(v.y); o.z = f2b(v.z); o.w = f2b(v.w);
    oa[i] = o;
  }
  for (int i = t0; i < nb4; i += step) {
    float4 v = b[i];
    ushort4 o; o.x = f2b(v.x); o.y = f2b(v.y); o.z = f2b(v.z); o.w = f2b(v.w);
    ob[i] = o;
  }
  for (int i = t0; i < nc4; i += step) {
    float4 v = c[i];
    ushort4 o; o.x = f2b(v.x); o.y = f2b(v.y); o.z = f2b(v.z); o.w = f2b(v.w);
    oc[i] = o;
  }
}

// ---------------- GEMM v4: C[m][n] = sum_k A[m][k]*B[n][k] (+bias) ----------------
// 4 waves (256 thr, 2x2 wave grid), wave-tile 64x96 (MR=4, NR=6): LDS re-read
// per block K-step drops 112->80 KB vs the 8-wave 2x4 grid, and MFMA per
// ds_read/barrier doubles (the round-7 kernel was LDS-pipe-bound: ~20 us of
// ds traffic at 85 B/clk/CU). BK=64, single-buffered (syncthreads drains
// vmcnt; stall hides under 3 co-resident blocks/CU). 128B LDS rows
// XOR-swizzled (rule 21, conflict-free round-5-verified). XCD-aware
// bijective remap (grid%8==0). EPI=0: QKV scatter epilogue; EPI=1: f32 out.
template <int BM, int EPI>
__global__ __launch_bounds__(256, 3) void gemm4(
    const u16* __restrict__ A, const u16* __restrict__ B,
    const float* __restrict__ bias, int M, int N, int K,
    u16* __restrict__ q_s, u16* __restrict__ k_s, u16* __restrict__ vt_s,
    float* __restrict__ outf) {
  constexpr int BN = 192;
  constexpr int MR = BM / 32;   // 16-row frags per wave (wave rows BM/2)
  constexpr int NR = 6;         // 16-col frags per wave (wave cols 96)
  constexpr int IA = BM / 32;   // gl_lds chunks per wave for A (1KB each)
  constexpr int IB = 6;         // 24KB B / 4 waves
  __shared__ __align__(16) u16 As[BM * 64];
  __shared__ __align__(16) u16 Bs[BN * 64];  // 24 KB
  const int tid = threadIdx.x;
  const int w = tid >> 6, l = tid & 63;
  const int lo = l & 15, hi = l >> 4;
  const int wr = w >> 1, wc = w & 1;
  // XCD-aware bijective remap (grid is a multiple of 8)
  const int nwg = gridDim.x * gridDim.y;
  int bid = blockIdx.y * gridDim.x + blockIdx.x;
  bid = (bid & 7) * (nwg >> 3) + (bid >> 3);
  const int bm0 = (bid / gridDim.x) * BM;
  const int bn0 = (bid % gridDim.x) * BN;
  const size_t Kb = (size_t)K * 2;
  const char* Ab = (const char*)A;
  const char* Bb = (const char*)B;
  const int lrow8 = l >> 3;        // row within a 1KB (8x128B) chunk
  const int lcol = (l & 7) * 16;   // 16B slot within the 128B row

  f32x4 acc[MR][NR] = {};

  for (int kt = 0; kt < K; kt += 64) {
    __syncthreads();  // prior reads of As/Bs done before overwrite
#pragma unroll
    for (int i = 0; i < IA; ++i) {
      int rl = (w * IA + i) * 8 + lrow8;
      int cb = lcol ^ ((rl & 7) << 4);  // inverse-swizzled source
      gl_lds16(Ab + (size_t)(bm0 + rl) * Kb + kt * 2 + cb,
               (char*)As + (w * IA + i) * 1024);
    }
#pragma unroll
    for (int i = 0; i < IB; ++i) {
      int rl = (w * IB + i) * 8 + lrow8;
      int cb = lcol ^ ((rl & 7) << 4);
      gl_lds16(Bb + (size_t)(bn0 + rl) * Kb + kt * 2 + cb,
               (char*)Bs + (w * IB + i) * 1024);
    }
    __syncthreads();  // compiler drains vmcnt(0) before barrier -> tile ready
#pragma unroll
    for (int ks = 0; ks < 2; ++ks) {
      bf16x8 bfr[NR];
#pragma unroll
      for (int nf = 0; nf < NR; ++nf) {
        int r = wc * 96 + nf * 16 + lo;
        bfr[nf] = ldf((char*)Bs + r * 128 + ((ks * 64 + hi * 16) ^ ((r & 7) << 4)));
      }
#pragma unroll
      for (int mf = 0; mf < MR; ++mf) {
        int r = wr * (MR * 16) + mf * 16 + lo;
        bf16x8 afr = ldf((char*)As + r * 128 + ((ks * 64 + hi * 16) ^ ((r & 7) << 4)));
#pragma unroll
        for (int nf = 0; nf < NR; ++nf) acc[mf][nf] = MFMA16(afr, bfr[nf], acc[mf][nf]);
      }
    }
  }

  // Epilogue. C/D layout: col = lo, row = hi*4 + reg (m89/m91-verified).
#pragma unroll
  for (int nf = 0; nf < NR; ++nf) {
    int col = bn0 + wc * 96 + nf * 16 + lo;
    float bv = bias[col];
    if (EPI == 0) {
      int seg = col / 768;  // 0=q 1=k 2=v (768 % BN == 0: uniform per block)
      int cs = col - seg * 768;
      int h = cs >> 6, d = cs & 63;
      u16* dst = (seg == 0) ? q_s : k_s;
#pragma unroll
      for (int mf = 0; mf < MR; ++mf) {
        int m0 = bm0 + wr * (MR * 16) + mf * 16 + hi * 4;
        int bb = m0 >> 10, t0 = m0 & 1023;
        size_t bh = (size_t)(bb * 12 + h);
        if (seg < 2) {
#pragma unroll
          for (int r = 0; r < 4; ++r)
            dst[(bh * 1024 + t0 + r) * 64 + d] = f2b(acc[mf][nf][r] + bv);
        } else {  // v transposed: 4 consecutive t -> one 8B store
          ushort4 pk;
          pk.x = f2b(acc[mf][nf][0] + bv);
          pk.y = f2b(acc[mf][nf][1] + bv);
          pk.z = f2b(acc[mf][nf][2] + bv);
          pk.w = f2b(acc[mf][nf][3] + bv);
          *(ushort4*)&vt_s[(bh * 64 + d) * 1024 + t0] = pk;
        }
      }
    } else {
#pragma unroll
      for (int mf = 0; mf < MR; ++mf) {
        int m0 = bm0 + wr * (MR * 16) + mf * 16 + hi * 4;
#pragma unroll
        for (int r = 0; r < 4; ++r) outf[(size_t)(m0 + r) * N + col] = acc[mf][nf][r] + bv;
      }
    }
  }
}

// ---------------- causal flash attention, v5 (unchanged from round 7) ----------------
__global__ __launch_bounds__(256) void attn_kernel(
    const u16* __restrict__ Q, const u16* __restrict__ Kg,
    const u16* __restrict__ Vt, u16* __restrict__ Y) {
  __shared__ __align__(16) u16 Ks[2][64 * 64];
  __shared__ __align__(16) u16 Vs[2][64 * 64];
  __shared__ __align__(16) u16 Ps[4][16 * 64];
  const int tid = threadIdx.x;
  const int w = tid >> 6, l = tid & 63;
  const int lo = l & 15, hi = l >> 4;
  // XCD-aware bijective remap (768 blocks % 8 == 0): same-bh blocks -> same XCD
  int bid = blockIdx.y * gridDim.x + blockIdx.x;
  bid = (bid & 7) * 96 + (bid >> 3);
  const int bh = bid >> 3;
  const int pr = bid & 7;  // 0..7 -> tiles {pr, 15-pr}
  const int b = bh / 12, h = bh % 12;
  const float c1 = 0.125f * 1.44269504f;  // scale * log2(e)
  char* pw = (char*)&Ps[w][0];
  const int swl = (lo & 7) << 4;
  const u16* Qb = Q + (size_t)bh * 65536;
  const char* Kbp = (const char*)(Kg + (size_t)bh * 65536);
  const char* Vbp = (const char*)(Vt + (size_t)bh * 65536);  // [64 d][1024 t]

  bf16x8 onesv;
#pragma unroll
  for (int j = 0; j < 8; ++j) onesv[j] = (__bf16)1.0f;

  auto STAGE = [&](int buf, int kb) {
#pragma unroll
    for (int i = 0; i < 2; ++i) {
      int c = w * 2 + i;
      int row = c * 8 + (l >> 3);                    // 8 rows (128B) / chunk
      int cb = ((l & 7) * 16) ^ ((row & 7) << 4);    // inverse-swizzled source
      gl_lds16(Kbp + (size_t)(kb + row) * 128 + cb, (char*)&Ks[buf][0] + c * 1024);
      gl_lds16(Vbp + (size_t)row * 2048 + (size_t)kb * 2 + cb, (char*)&Vs[buf][0] + c * 1024);
    }
  };

  for (int sg = 0; sg < 2; ++sg) {
    const int tile = sg ? (15 - pr) : pr;
    const int q0 = tile * 64 + w * 16;  // wave's 16 q-rows
    const int nt = tile + 1;            // KV tiles of 64

    bf16x8 qf[2];
#pragma unroll
    for (int ks = 0; ks < 2; ++ks)
      qf[ks] = ldf(Qb + (size_t)(q0 + lo) * 64 + ks * 32 + hi * 8);

    f32x4 o[4] = {};
    f32x4 mrow, lsum;
#pragma unroll
    for (int r = 0; r < 4; ++r) { mrow[r] = -1e30f; lsum[r] = 0.0f; }

    STAGE(0, 0);
    for (int kt = 0; kt < nt; ++kt) {
      const int cur = kt & 1;
      if (kt + 1 < nt) {
        STAGE(cur ^ 1, (kt + 1) * 64);
        asm volatile("s_waitcnt vmcnt(4)" ::: "memory");  // prev stage landed
      } else {
        asm volatile("s_waitcnt vmcnt(0)" ::: "memory");
      }
      __builtin_amdgcn_s_barrier();
      __builtin_amdgcn_sched_barrier(0);
      const char* Kt = (const char*)&Ks[cur][0];
      const char* Vv = (const char*)&Vs[cur][0];
      const int kb = kt * 64;

      // ---- QK^T: S[q=row][k=col]
      f32x4 sv[4] = {};
      __builtin_amdgcn_s_setprio(1);
#pragma unroll
      for (int kf = 0; kf < 4; ++kf) {
        int rb = (kf * 16 + lo) * 128;
#pragma unroll
        for (int ks = 0; ks < 2; ++ks)
          sv[kf] = MFMA16(qf[ks], ldf(Kt + rb + ((ks * 64 + hi * 16) ^ swl)), sv[kf]);
      }
      __builtin_amdgcn_s_setprio(0);
      // ---- V frags hoisted: lgkm latency hides under softmax VALU
      bf16x8 vb[4][2];
#pragma unroll
      for (int nd = 0; nd < 4; ++nd) {
        int rb = (nd * 16 + lo) * 128;
#pragma unroll
        for (int ks = 0; ks < 2; ++ks)
          vb[nd][ks] = ldf(Vv + rb + ((ks * 64 + hi * 16) ^ swl));
      }
      // ---- causal mask (only diagonal tile crosses)
      if (kt == nt - 1) {
#pragma unroll
        for (int kf = 0; kf < 4; ++kf)
#pragma unroll
          for (int r = 0; r < 4; ++r) {
            int qrow = q0 + hi * 4 + r;
            int kcol = kb + kf * 16 + lo;
            if (kcol > qrow) sv[kf][r] = -1e30f;
          }
      }
      // ---- online softmax with defer-max (row = (hi,r); 16 lo-lanes/row)
      f32x4 lm = sv[0];
#pragma unroll
      for (int kf = 1; kf < 4; ++kf)
#pragma unroll
        for (int r = 0; r < 4; ++r) lm[r] = fmaxf(lm[r], sv[kf][r]);
      bool need = false;
#pragma unroll
      for (int r = 0; r < 4; ++r) need |= (lm[r] * c1 > mrow[r] + 8.0f);
      if (__any(need)) {
#pragma unroll
        for (int st = 1; st < 16; st <<= 1)
#pragma unroll
          for (int r = 0; r < 4; ++r) lm[r] = fmaxf(lm[r], __shfl_xor(lm[r], st));
        f32x4 al;
#pragma unroll
        for (int r = 0; r < 4; ++r) {
          float Mn = fmaxf(mrow[r], lm[r] * c1);
          al[r] = __builtin_amdgcn_exp2f(mrow[r] - Mn);
          mrow[r] = Mn;
          lsum[r] *= al[r];
        }
#pragma unroll
        for (int nd = 0; nd < 4; ++nd)
#pragma unroll
          for (int r = 0; r < 4; ++r) o[nd][r] *= al[r];
      }
      // P = exp2(S*c1 - m); rowsum comes from the ones-MFMA below.
#pragma unroll
      for (int kf = 0; kf < 4; ++kf)
#pragma unroll
        for (int r = 0; r < 4; ++r)
          sv[kf][r] = __builtin_amdgcn_exp2f(fmaf(sv[kf][r], c1, -mrow[r]));
      // ---- P -> per-wave LDS (swizzled), reload as A-frag
#pragma unroll
      for (int kf = 0; kf < 4; ++kf)
#pragma unroll
        for (int r = 0; r < 4; ++r) {
          int qrow = hi * 4 + r;
          int cb = ((lo + kf * 16) * 2) ^ ((qrow & 7) << 4);
          *(u16*)(pw + qrow * 128 + cb) = f2b(sv[kf][r]);
        }
      bf16x8 pa[2];
#pragma unroll
      for (int ks = 0; ks < 2; ++ks)
        pa[ks] = ldf(pw + lo * 128 + ((ks * 64 + hi * 16) ^ swl));
      // ---- PV: O[q][d] += P[q][k] V[k][d]; rowsum l += P·1 (ones-MFMA)
      __builtin_amdgcn_s_setprio(1);
#pragma unroll
      for (int ks = 0; ks < 2; ++ks) {
#pragma unroll
        for (int nd = 0; nd < 4; ++nd) o[nd] = MFMA16(pa[ks], vb[nd][ks], o[nd]);
        lsum = MFMA16(pa[ks], onesv, lsum);
      }
      __builtin_amdgcn_s_setprio(0);
      __builtin_amdgcn_sched_barrier(0);
      __builtin_amdgcn_s_barrier();  // all reads of cur done before re-stage
    }

    // ---- epilogue: y[b][t][h*64+d] bf16
    f32x4 inv;
#pragma unroll
    for (int r = 0; r < 4; ++r) inv[r] = 1.0f / lsum[r];
#pragma unroll
    for (int nd = 0; nd < 4; ++nd)
#pragma unroll
      for (int r = 0; r < 4; ++r) {
        int t = q0 + hi * 4 + r;
        int d = nd * 16 + lo;
        Y[((size_t)b * 1024 + t) * 768 + h * 64 + d] = f2b(o[nd][r] * inv[r]);
      }
  }
}

// ---------------- launcher ----------------
extern "C" void kernel_launch(void* const* d_in, const int* in_sizes, int n_in,
                              void* d_out, int out_size, void* d_ws, size_t ws_size,
                              hipStream_t stream) {
  const float* x  = (const float*)d_in[0];
  const float* Wa = (const float*)d_in[1];
  const float* ba = (const float*)d_in[2];
  const float* Wp = (const float*)d_in[3];
  const float* bp = (const float*)d_in[4];
  float* out = (float*)d_out;
  char* ws = (char*)d_ws;

  constexpr size_t XB  = 0;                       // x bf16   [8192][768]
  constexpr size_t WAB = 12582912;                // W_attn bf16 [2304][768]
  constexpr size_t WPB = WAB + 3538944;           // W_proj bf16 [768][768]
  constexpr size_t QS  = WPB + 1179648;           // q bf16 [96][1024][64]
  constexpr size_t KS  = QS + 12582912;           // k bf16 [96][1024][64]
  constexpr size_t VTS = KS + 12582912;           // v^T bf16 [96][64][1024]
  constexpr size_t YB  = VTS + 12582912;          // y bf16 [8192][768]

  u16* xb  = (u16*)(ws + XB);
  u16* wab = (u16*)(ws + WAB);
  u16* wpb = (u16*)(ws + WPB);
  u16* qs  = (u16*)(ws + QS);
  u16* ks  = (u16*)(ws + KS);
  u16* vts = (u16*)(ws + VTS);
  u16* yb  = (u16*)(ws + YB);

  cvt3_kernel<<<2048, 256, 0, stream>>>(
      (const float4*)x,  (ushort4*)xb,  8192 * 768 / 4,
      (const float4*)Wa, (ushort4*)wab, 2304 * 768 / 4,
      (const float4*)Wp, (ushort4*)wpb, 768 * 768 / 4);

  gemm4<128, 0><<<dim3(12, 64), 256, 0, stream>>>(xb, wab, ba, 8192, 2304, 768,
                                                  qs, ks, vts, nullptr);
  attn_kernel<<<dim3(8, 96), 256, 0, stream>>>(qs, ks, vts, yb);
  gemm4<64, 1><<<dim3(4, 128), 256, 0, stream>>>(yb, wpb, bp, 8192, 768, 768,
                                                 nullptr, nullptr, nullptr, out);
}